// Round 15
// baseline (730.658 us; speedup 1.0000x reference)
//
#include <hip/hip_runtime.h>
#include <hip/hip_bf16.h>

// One-hot: label (H*W int32) -> out (N, H, W) float32.
// Minimum possible traffic (fused) = 64R + 512W = 576 MB (~88-95 us at copy-class).
//
// Journal:
//  R1 (8 plane-streams/thread, read-once):    130 us (8 concurrent 64MiB-apart write windows = 4.6 TB/s)
//  R3 (nontemporal stores):                   250 us (nt bypasses L2 write-combine; never again)
//  R4 (plane per blockIdx.y, int32 reads):    146 us (single write window fast; label re-fetch thrash)
//  R5 (wave-per-plane, staggered):            153 us (8 concurrent aliased windows)
//  R6 (pack u8 + 16px/thread expand):         185 us (per-THREAD-contiguous accesses broke coalescing)
//  R7 (pack u8 + plane-serial):               118 us (two-pass champion structure)
//  R8 (bitplanes v1):                         128 us (k1 strided reads; k2 broadcast gmem reads)
//  R9 (fused, NO phase lock):                 129 us (block drift -> R1 regime)
//  R10 (R7 + coalesced k1, fewer k2 WGs):     120 us (both immaterial)
//  R11 (4-bit pack, 8 MiB intermediate):      112 us (champion)
//  R12 (cooperative grid.sync fusion):        FAILED (coop launch silently unsupported here)
//  R13 (bitplanes v2, ballot k1):             149 us (divergent scattered k1 stores)
//  R14 (bitplanes v3, LDS-engineered):        136 us BUT k2 FETCH=8.2MB proves read-traffic was
//                                              already immaterial -> re-read elimination exhausted.
//
// R15: FUSED + SOFT grid barrier. Each block packs its 16384-px chunk into
// 8 VGPRs (4-bit), then phases plane 0..7 writes behind a device-scope
// atomic counter barrier (capped spin -> deadlock-impossible; correctness
// never depends on the barrier, it only aligns the write windows so one
// 64 MiB plane window is in flight at a time = R4/R7/R11's proven regime).
// Zero intermediate traffic, no second dispatch, no packed re-reads.

typedef unsigned int u32;

#define CHUNK 16384   // px per block -> 1024 blocks for 4096^2
#define ITERS 16      // CHUNK / (256 thr * 4 px)

__device__ __forceinline__ void soft_barrier(u32* counter, u32 target) {
    __syncthreads();
    if (threadIdx.x == 0) {
        __hip_atomic_fetch_add(counter, 1u, __ATOMIC_RELAXED, __HIP_MEMORY_SCOPE_AGENT);
        int spins = 0;
        while (__hip_atomic_load(counter, __ATOMIC_RELAXED, __HIP_MEMORY_SCOPE_AGENT) < target
               && spins < (1 << 19)) {
            ++spins;
        }
    }
    __syncthreads();
}

__global__ void __launch_bounds__(256) onehot_fused_kernel(
    const int* __restrict__ label, float* __restrict__ out,
    u32* __restrict__ counter, int total) {
    const int tid = threadIdx.x;
    const u32 nblk = gridDim.x;
    const long long base = (long long)blockIdx.x * CHUNK;

    // Pack 64 labels/thread into 8 u32 (4 bits each); every load is
    // lane-contiguous (1 KiB/wave/instr).
    u32 pk[ITERS / 2];
#pragma unroll
    for (int i = 0; i < ITERS / 2; ++i) pk[i] = 0;
#pragma unroll
    for (int it = 0; it < ITERS; ++it) {
        int4 a = *reinterpret_cast<const int4*>(label + base + it * 1024 + tid * 4);
        u32 nib = (u32)(a.x & 7) | ((u32)(a.y & 7) << 4) |
                  ((u32)(a.z & 7) << 8) | ((u32)(a.w & 7) << 12);
        pk[it >> 1] |= nib << ((it & 1) * 16);
    }

    // Phase-align all blocks before the first write window.
    soft_barrier(counter, nblk);

    for (int n = 0; n < 8; ++n) {
        float* op = out + (long long)n * total + base;
#pragma unroll
        for (int it = 0; it < ITERS; ++it) {
            u32 q = pk[it >> 1] >> ((it & 1) * 16);
            float4 v;
            v.x = (((q      ) & 15u) == (u32)n) ? 1.0f : 0.0f;
            v.y = (((q >> 4 ) & 15u) == (u32)n) ? 1.0f : 0.0f;
            v.z = (((q >> 8 ) & 15u) == (u32)n) ? 1.0f : 0.0f;
            v.w = (((q >> 12) & 15u) == (u32)n) ? 1.0f : 0.0f;
            *reinterpret_cast<float4*>(op + it * 1024 + tid * 4) = v;
        }
        if (n < 7) soft_barrier(counter, nblk * (u32)(n + 2));
    }
}

// ---- R11 two-pass fallback ----

__global__ void __launch_bounds__(256) pack_labels_kernel(
    const int* __restrict__ label, u32* __restrict__ packed) {
    const int tid = threadIdx.x;
    const long long base = (long long)blockIdx.x * 4096;
    u32* wp = packed + (base >> 3);
#pragma unroll
    for (int q = 0; q < 2; ++q) {
        const int* lp = label + base + q * 2048 + tid * 4;
        int4 a = *reinterpret_cast<const int4*>(lp);
        int4 b = *reinterpret_cast<const int4*>(lp + 1024);
        u32 w = (u32)(a.x & 7)        | ((u32)(a.y & 7) << 4)  |
                ((u32)(a.z & 7) << 8) | ((u32)(a.w & 7) << 12) |
                ((u32)(b.x & 7) << 16)| ((u32)(b.y & 7) << 20) |
                ((u32)(b.z & 7) << 24)| ((u32)(b.w & 7) << 28);
        wp[q * 256 + tid] = w;
    }
}

__global__ void __launch_bounds__(256) expand_kernel(
    const u32* __restrict__ packed, float* __restrict__ out, int total) {
    const u32 n = blockIdx.y;
    const int tid = threadIdx.x;
    const long long base = (long long)blockIdx.x * 4096;
    const u32* wp = packed + (base >> 3);
    float* op = out + (long long)n * total + base;
#pragma unroll
    for (int q = 0; q < 2; ++q) {
        u32 w = wp[q * 256 + tid];
        float4 v0, v1;
        v0.x = (((w      ) & 15u) == n) ? 1.0f : 0.0f;
        v0.y = (((w >> 4 ) & 15u) == n) ? 1.0f : 0.0f;
        v0.z = (((w >> 8 ) & 15u) == n) ? 1.0f : 0.0f;
        v0.w = (((w >> 12) & 15u) == n) ? 1.0f : 0.0f;
        v1.x = (((w >> 16) & 15u) == n) ? 1.0f : 0.0f;
        v1.y = (((w >> 20) & 15u) == n) ? 1.0f : 0.0f;
        v1.z = (((w >> 24) & 15u) == n) ? 1.0f : 0.0f;
        v1.w = (((w >> 28)       ) == n) ? 1.0f : 0.0f;
        float* o = op + q * 2048 + tid * 4;
        *reinterpret_cast<float4*>(o)        = v0;
        *reinterpret_cast<float4*>(o + 1024) = v1;
    }
}

__global__ void __launch_bounds__(256) get_one_hot_generic_kernel(
    const int* __restrict__ label, float* __restrict__ out,
    int total, int N) {
    long long i = ((long long)blockIdx.x * blockDim.x + threadIdx.x) * 4;
    if (i >= total) return;
    int4 lab = *reinterpret_cast<const int4*>(label + i);
    for (int n = 0; n < N; ++n) {
        float4 v;
        v.x = (lab.x == n) ? 1.0f : 0.0f;
        v.y = (lab.y == n) ? 1.0f : 0.0f;
        v.z = (lab.z == n) ? 1.0f : 0.0f;
        v.w = (lab.w == n) ? 1.0f : 0.0f;
        *reinterpret_cast<float4*>(out + (long long)n * total + i) = v;
    }
}

extern "C" void kernel_launch(void* const* d_in, const int* in_sizes, int n_in,
                              void* d_out, int out_size, void* d_ws, size_t ws_size,
                              hipStream_t stream) {
    const int* label = (const int*)d_in[0];
    float* out = (float*)d_out;

    int total = in_sizes[0];          // H*W = 16,777,216
    int N = out_size / total;         // 8

    int blocks = total / CHUNK;       // 1024
    if (N == 8 && total % CHUNK == 0 && blocks <= 2048 && ws_size >= 8) {
        // zero the barrier counter, then fused single-pass
        hipMemsetAsync(d_ws, 0, 8, stream);
        onehot_fused_kernel<<<blocks, 256, 0, stream>>>(label, out, (u32*)d_ws, total);
    } else if (N == 8 && total % 4096 == 0 && ws_size >= (size_t)(total / 2)) {
        int b = total / 4096;
        pack_labels_kernel<<<b, 256, 0, stream>>>(label, (u32*)d_ws);
        dim3 grid(b, N);
        expand_kernel<<<grid, 256, 0, stream>>>((const u32*)d_ws, out, total);
    } else {
        int grid = (total / 4 + 255) / 256;
        get_one_hot_generic_kernel<<<grid, 256, 0, stream>>>(label, out, total, N);
    }
}

// Round 16
// 112.144 us; speedup vs baseline: 6.5153x; 6.5153x over previous
//
#include <hip/hip_runtime.h>
#include <hip/hip_bf16.h>

// One-hot: label (H*W int32) -> out (N, H, W) float32.
// Two-pass realistic floor ~101-103 us (576 MB core traffic + 72 MB pack pass
// at the ~6.3 TB/s mixed-stream rate demonstrated by R4).
//
// Journal (final):
//  R1 (8 plane-streams/thread, read-once):    130 us (8 concurrent 64MiB-apart write windows = 4.6 TB/s)
//  R3 (nontemporal stores):                   250 us (nt bypasses L2 write-combine; never again)
//  R4 (plane per blockIdx.y, int32 reads):    146 us (single write window ~6.3 TB/s; label re-fetch thrash)
//  R5 (wave-per-plane, staggered):            153 us (8 concurrent aliased windows)
//  R6 (pack u8 + 16px/thread expand):         185 us (per-THREAD-contiguous accesses broke coalescing)
//  R7 (pack u8 + plane-serial):               118 us (two-pass champion structure)
//  R8 (bitplanes v1):                         128 us (k1 strided reads; k2 broadcast gmem reads)
//  R9 (fused, NO phase lock):                 129 us (block drift -> R1 regime)
//  R10 (R7 + coalesced k1, fewer k2 WGs):     120 us (both immaterial)
//  R11 (4-bit pack, 8 MiB intermediate):      112 us  <-- CHAMPION
//  R12 (cooperative grid.sync fusion):        FAILED (coop launch silently unsupported in harness)
//  R13 (bitplanes v2, ballot k1):             149 us (divergent scattered k1 stores)
//  R14 (bitplanes v3, LDS-engineered):        136 us (k2 FETCH=8.2MB: reads already immaterial ->
//                                              re-read elimination exhausted as a lever)
//  R15 (fused + soft atomic barrier):         730 us (spin cost >> 80 MB saved; cross-XCD counter
//                                              hammering. ALL fusion routes now exhausted)
//
// Conclusion: dispatcher-enforced plane-serial two-pass (this kernel) is the
// structural optimum available in this harness. Residual gap vs floor is the
// mixed read/write stream regime + the 11 us pack pass.

typedef unsigned int u32;

// k1: block packs 4096 px -> 512 words (4-bit labels). 2 iterations x
// (2 int4 loads @1KiB/wave, 1 u32 store @256B/wave). All lane-contiguous.
__global__ void __launch_bounds__(256) pack_labels_kernel(
    const int* __restrict__ label, u32* __restrict__ packed) {
    const int tid = threadIdx.x;
    const long long base = (long long)blockIdx.x * 4096;
    u32* wp = packed + (base >> 3);
#pragma unroll
    for (int q = 0; q < 2; ++q) {
        const int* lp = label + base + q * 2048 + tid * 4;
        int4 a = *reinterpret_cast<const int4*>(lp);          // px p..p+3
        int4 b = *reinterpret_cast<const int4*>(lp + 1024);   // px p+1024..p+1027
        u32 w = (u32)(a.x & 7)        | ((u32)(a.y & 7) << 4)  |
                ((u32)(a.z & 7) << 8) | ((u32)(a.w & 7) << 12) |
                ((u32)(b.x & 7) << 16)| ((u32)(b.y & 7) << 20) |
                ((u32)(b.z & 7) << 24)| ((u32)(b.w & 7) << 28);
        wp[q * 256 + tid] = w;
    }
}

// k2: one plane per blockIdx.y (x fastest -> dispatcher-enforced plane-serial
// write windows = the proven fast regime). Block expands 4096 px:
// 2 x (1 u32 load @256B/wave, 2 float4 stores @1KiB/wave).
__global__ void __launch_bounds__(256) expand_kernel(
    const u32* __restrict__ packed, float* __restrict__ out, int total) {
    const u32 n = blockIdx.y;
    const int tid = threadIdx.x;
    const long long base = (long long)blockIdx.x * 4096;
    const u32* wp = packed + (base >> 3);
    float* op = out + (long long)n * total + base;
#pragma unroll
    for (int q = 0; q < 2; ++q) {
        u32 w = wp[q * 256 + tid];
        float4 v0, v1;
        v0.x = (((w      ) & 15u) == n) ? 1.0f : 0.0f;
        v0.y = (((w >> 4 ) & 15u) == n) ? 1.0f : 0.0f;
        v0.z = (((w >> 8 ) & 15u) == n) ? 1.0f : 0.0f;
        v0.w = (((w >> 12) & 15u) == n) ? 1.0f : 0.0f;
        v1.x = (((w >> 16) & 15u) == n) ? 1.0f : 0.0f;
        v1.y = (((w >> 20) & 15u) == n) ? 1.0f : 0.0f;
        v1.z = (((w >> 24) & 15u) == n) ? 1.0f : 0.0f;
        v1.w = (((w >> 28)       ) == n) ? 1.0f : 0.0f;
        float* o = op + q * 2048 + tid * 4;
        *reinterpret_cast<float4*>(o)        = v0;
        *reinterpret_cast<float4*>(o + 1024) = v1;
    }
}

// Fallback (R1 structure) if N != 8 or shape doesn't divide.
__global__ void __launch_bounds__(256) get_one_hot_generic_kernel(
    const int* __restrict__ label, float* __restrict__ out,
    int total, int N) {
    long long i = ((long long)blockIdx.x * blockDim.x + threadIdx.x) * 4;
    if (i >= total) return;
    int4 lab = *reinterpret_cast<const int4*>(label + i);
    for (int n = 0; n < N; ++n) {
        float4 v;
        v.x = (lab.x == n) ? 1.0f : 0.0f;
        v.y = (lab.y == n) ? 1.0f : 0.0f;
        v.z = (lab.z == n) ? 1.0f : 0.0f;
        v.w = (lab.w == n) ? 1.0f : 0.0f;
        *reinterpret_cast<float4*>(out + (long long)n * total + i) = v;
    }
}

extern "C" void kernel_launch(void* const* d_in, const int* in_sizes, int n_in,
                              void* d_out, int out_size, void* d_ws, size_t ws_size,
                              hipStream_t stream) {
    const int* label = (const int*)d_in[0];
    float* out = (float*)d_out;

    int total = in_sizes[0];          // H*W = 16,777,216
    int N = out_size / total;         // 8

    bool fast = (N == 8) && (total % 4096 == 0) && (ws_size >= (size_t)(total / 2));
    if (fast) {
        int blocks = total / 4096;    // 4096
        pack_labels_kernel<<<blocks, 256, 0, stream>>>(label, (u32*)d_ws);
        dim3 grid(blocks, N);         // 4096 x 8; x fastest -> plane-serial passes
        expand_kernel<<<grid, 256, 0, stream>>>((const u32*)d_ws, out, total);
    } else {
        int grid = (total / 4 + 255) / 256;
        get_one_hot_generic_kernel<<<grid, 256, 0, stream>>>(label, out, total, N);
    }
}